// Round 2
// baseline (509.420 us; speedup 1.0000x reference)
//
#include <hip/hip_runtime.h>
#include <hip/hip_bf16.h>

// RNN-T joint: out[b,t,u,v] = sum_h relu(enc[b,t,h]+pred[b,u,h]) * W_out[h,v] + b_out[v]
// E=512, P=640, H=512, V=1024, B=4, T=256, U=64  -> M = 65536
// Strategy: bf16 MFMA (16x16x32) for all GEMMs, fp32 accumulate.

typedef __attribute__((ext_vector_type(4))) float f32x4;
typedef __attribute__((ext_vector_type(8))) short bf16x8;

__device__ __forceinline__ short f2bf(float x) {
    return __builtin_bit_cast(short, __float2bfloat16(x));
}

// swizzled byte offset inside a [rows][64 bf16] LDS tile (row stride 128 B)
__device__ __forceinline__ int swz(int r, int kByte) {
    return r * 128 + (kByte ^ ((r & 7) << 4));
}

// ---------------------------------------------------------------------------
// transpose + cast: in[R][C] f32  ->  out[C][R] bf16
// ---------------------------------------------------------------------------
__global__ void transpose_cast(const float* __restrict__ in, short* __restrict__ out,
                               int R, int C) {
    __shared__ float tile[32][33];
    const int c0 = blockIdx.x * 32, r0 = blockIdx.y * 32;
    const int tx = threadIdx.x, ty = threadIdx.y; // (32,8)
    #pragma unroll
    for (int i = 0; i < 32; i += 8) {
        int r = r0 + ty + i, c = c0 + tx;
        if (r < R && c < C) tile[ty + i][tx] = in[(size_t)r * C + c];
    }
    __syncthreads();
    #pragma unroll
    for (int i = 0; i < 32; i += 8) {
        int oc = c0 + ty + i;  // output row (= input col)
        int orr = r0 + tx;     // output col (= input row)
        if (oc < C && orr < R) out[(size_t)oc * R + orr] = f2bf(tile[tx][ty + i]);
    }
}

// ---------------------------------------------------------------------------
// generic projection GEMM: C[M][N] = A[M][K](f32, cast->bf16) * BT[N][K](bf16) + bias
// BM=BN=128, BK=64, 256 threads (4 waves 2x2), grid (M/128, N/128)
// ---------------------------------------------------------------------------
__global__ __launch_bounds__(256, 2)
void proj_kernel(const float* __restrict__ A, const short* __restrict__ BT,
                 const float* __restrict__ bias, float* __restrict__ C,
                 int M, int N, int K) {
    __shared__ __align__(16) unsigned char lA[128 * 128];
    __shared__ __align__(16) unsigned char lB[128 * 128];

    const int tid = threadIdx.x;
    const int m0 = blockIdx.x * 128;
    const int n0 = blockIdx.y * 128;

    const int rSt = tid >> 3;          // staging row (+ it*32)
    const int kc  = tid & 7;           // staging k-chunk (8 floats each)

    const int wave = tid >> 6, lane = tid & 63;
    const int wr = wave >> 1, wc = wave & 1;
    const int rA0 = wr * 64 + (lane & 15);
    const int rB0 = wc * 64 + (lane & 15);
    const int kHi = (lane >> 4) * 16;  // byte offset of this lane's k-group

    f32x4 acc[4][4];
    #pragma unroll
    for (int i = 0; i < 4; ++i)
        #pragma unroll
        for (int j = 0; j < 4; ++j) acc[i][j] = (f32x4)0.0f;

    for (int k0 = 0; k0 < K; k0 += 64) {
        // stage A (f32 -> bf16) into lA
        #pragma unroll
        for (int it = 0; it < 4; ++it) {
            int r = rSt + it * 32;
            const float* ap = A + (size_t)(m0 + r) * K + k0 + kc * 8;
            f32x4 a0 = *(const f32x4*)ap;
            f32x4 a1 = *(const f32x4*)(ap + 4);
            bf16x8 v;
            v[0] = f2bf(a0[0]); v[1] = f2bf(a0[1]); v[2] = f2bf(a0[2]); v[3] = f2bf(a0[3]);
            v[4] = f2bf(a1[0]); v[5] = f2bf(a1[1]); v[6] = f2bf(a1[2]); v[7] = f2bf(a1[3]);
            *(bf16x8*)(lA + swz(r, kc * 16)) = v;
        }
        // stage B (already bf16, k-contiguous)
        #pragma unroll
        for (int it = 0; it < 4; ++it) {
            int rn = rSt + it * 32;
            const short* wp = BT + (size_t)(n0 + rn) * K + k0 + kc * 8;
            *(bf16x8*)(lB + swz(rn, kc * 16)) = *(const bf16x8*)wp;
        }
        __syncthreads();
        #pragma unroll
        for (int ks = 0; ks < 2; ++ks) {
            const int kb = ks * 64 + kHi;
            bf16x8 af[4], bf[4];
            #pragma unroll
            for (int i = 0; i < 4; ++i) af[i] = *(const bf16x8*)(lA + swz(rA0 + i * 16, kb));
            #pragma unroll
            for (int j = 0; j < 4; ++j) bf[j] = *(const bf16x8*)(lB + swz(rB0 + j * 16, kb));
            #pragma unroll
            for (int i = 0; i < 4; ++i)
                #pragma unroll
                for (int j = 0; j < 4; ++j)
                    acc[i][j] = __builtin_amdgcn_mfma_f32_16x16x32_bf16(af[i], bf[j], acc[i][j], 0, 0, 0);
        }
        __syncthreads();
    }

    // epilogue: C = acc + bias
    #pragma unroll
    for (int i = 0; i < 4; ++i) {
        #pragma unroll
        for (int j = 0; j < 4; ++j) {
            int col = n0 + wc * 64 + j * 16 + (lane & 15);
            float bo = bias[col];
            #pragma unroll
            for (int rg = 0; rg < 4; ++rg) {
                int row = m0 + wr * 64 + i * 16 + (lane >> 4) * 4 + rg;
                C[(size_t)row * N + col] = acc[i][j][rg] + bo;
            }
        }
    }
}

// ---------------------------------------------------------------------------
// fused joint kernel: out[m][v], m=(b*256+t)*64+u, A generated on the fly:
//   A[m][h] = relu(encA[b,t,h] + predA[b,u,h])  (bf16)
// 128x128 tile, K=512, BK=64. grid (512, 8), 256 threads.
// ---------------------------------------------------------------------------
__global__ __launch_bounds__(256, 2)
void joint_kernel(const float* __restrict__ encA,   // [1024][512]
                  const float* __restrict__ predA,  // [256][512]
                  const short* __restrict__ WoutT,  // [1024][512] bf16
                  const float* __restrict__ b_out,  // [1024]
                  float* __restrict__ out) {        // [65536][1024]
    __shared__ __align__(16) unsigned char lA[128 * 128];
    __shared__ __align__(16) unsigned char lB[128 * 128];

    const int tid = threadIdx.x;
    const int m0 = blockIdx.x * 128;
    const int n0 = blockIdx.y * 128;
    const int b  = m0 >> 14;
    const int t0 = (m0 >> 6) & 255;

    const int rSt = tid >> 3;
    const int kc  = tid & 7;

    const int wave = tid >> 6, lane = tid & 63;
    const int wr = wave >> 1, wc = wave & 1;
    const int rA0 = wr * 64 + (lane & 15);
    const int rB0 = wc * 64 + (lane & 15);
    const int kHi = (lane >> 4) * 16;

    const float* encB  = encA + (size_t)(b * 256 + t0) * 512;
    const float* predB = predA + (size_t)(b * 64) * 512;

    f32x4 acc[4][4];
    #pragma unroll
    for (int i = 0; i < 4; ++i)
        #pragma unroll
        for (int j = 0; j < 4; ++j) acc[i][j] = (f32x4)0.0f;

    for (int k0 = 0; k0 < 512; k0 += 64) {
        // stage A: joint tile = relu(enc + pred) -> bf16
        #pragma unroll
        for (int it = 0; it < 4; ++it) {
            int r = rSt + it * 32;
            int tt = r >> 6;       // 0 or 1
            int u  = r & 63;
            const float* ep = encB + (size_t)tt * 512 + k0 + kc * 8;
            const float* pp = predB + (size_t)u * 512 + k0 + kc * 8;
            f32x4 e0 = *(const f32x4*)ep;
            f32x4 e1 = *(const f32x4*)(ep + 4);
            f32x4 p0 = *(const f32x4*)pp;
            f32x4 p1 = *(const f32x4*)(pp + 4);
            bf16x8 v;
            v[0] = f2bf(fmaxf(e0[0] + p0[0], 0.f));
            v[1] = f2bf(fmaxf(e0[1] + p0[1], 0.f));
            v[2] = f2bf(fmaxf(e0[2] + p0[2], 0.f));
            v[3] = f2bf(fmaxf(e0[3] + p0[3], 0.f));
            v[4] = f2bf(fmaxf(e1[0] + p1[0], 0.f));
            v[5] = f2bf(fmaxf(e1[1] + p1[1], 0.f));
            v[6] = f2bf(fmaxf(e1[2] + p1[2], 0.f));
            v[7] = f2bf(fmaxf(e1[3] + p1[3], 0.f));
            *(bf16x8*)(lA + swz(r, kc * 16)) = v;
        }
        // stage B: W_outT tile (bf16, k-contiguous)
        #pragma unroll
        for (int it = 0; it < 4; ++it) {
            int rn = rSt + it * 32;
            const short* wp = WoutT + (size_t)(n0 + rn) * 512 + k0 + kc * 8;
            *(bf16x8*)(lB + swz(rn, kc * 16)) = *(const bf16x8*)wp;
        }
        __syncthreads();
        #pragma unroll
        for (int ks = 0; ks < 2; ++ks) {
            const int kb = ks * 64 + kHi;
            bf16x8 af[4], bf[4];
            #pragma unroll
            for (int i = 0; i < 4; ++i) af[i] = *(const bf16x8*)(lA + swz(rA0 + i * 16, kb));
            #pragma unroll
            for (int j = 0; j < 4; ++j) bf[j] = *(const bf16x8*)(lB + swz(rB0 + j * 16, kb));
            #pragma unroll
            for (int i = 0; i < 4; ++i)
                #pragma unroll
                for (int j = 0; j < 4; ++j)
                    acc[i][j] = __builtin_amdgcn_mfma_f32_16x16x32_bf16(af[i], bf[j], acc[i][j], 0, 0, 0);
        }
        __syncthreads();
    }

    // epilogue: out = acc + b_out
    #pragma unroll
    for (int i = 0; i < 4; ++i) {
        #pragma unroll
        for (int j = 0; j < 4; ++j) {
            int col = n0 + wc * 64 + j * 16 + (lane & 15);
            float bo = b_out[col];
            #pragma unroll
            for (int rg = 0; rg < 4; ++rg) {
                int row = m0 + wr * 64 + i * 16 + (lane >> 4) * 4 + rg;
                out[(size_t)row * 1024 + col] = acc[i][j][rg] + bo;
            }
        }
    }
}

// ---------------------------------------------------------------------------
extern "C" void kernel_launch(void* const* d_in, const int* in_sizes, int n_in,
                              void* d_out, int out_size, void* d_ws, size_t ws_size,
                              hipStream_t stream) {
    const float* enc_in  = (const float*)d_in[0];  // (4,256,512)
    const float* pred_in = (const float*)d_in[1];  // (4,64,640)
    const float* W_enc   = (const float*)d_in[2];  // (512,512)
    const float* b_enc   = (const float*)d_in[3];  // (512,)
    const float* W_pred  = (const float*)d_in[4];  // (640,512)
    const float* b_pred  = (const float*)d_in[5];  // (512,)
    const float* W_out   = (const float*)d_in[6];  // (512,1024)
    const float* b_out   = (const float*)d_in[7];  // (1024,)
    float* out = (float*)d_out;                    // (4,256,64,1024)

    // workspace layout
    char* ws = (char*)d_ws;
    float* encA   = (float*)(ws);                  // 1024*512 f32   = 2 MB
    float* predA  = (float*)(ws + 2097152);        //  256*512 f32   = 0.5 MB
    short* WencT  = (short*)(ws + 2621440);        // [512][512] bf16
    short* WpredT = (short*)(ws + 3145728);        // [512][640] bf16
    short* WoutT  = (short*)(ws + 3801088);        // [1024][512] bf16

    dim3 tb(32, 8);
    // W_enc [512][512] -> WencT [512][512]
    transpose_cast<<<dim3(512 / 32, 512 / 32), tb, 0, stream>>>(W_enc, WencT, 512, 512);
    // W_pred [640][512] -> WpredT [512][640]
    transpose_cast<<<dim3(512 / 32, 640 / 32), tb, 0, stream>>>(W_pred, WpredT, 640, 512);
    // W_out [512][1024] -> WoutT [1024][512]
    transpose_cast<<<dim3(1024 / 32, 512 / 32), tb, 0, stream>>>(W_out, WoutT, 512, 1024);

    // projections
    proj_kernel<<<dim3(1024 / 128, 512 / 128), 256, 0, stream>>>(
        enc_in, WencT, b_enc, encA, 1024, 512, 512);
    proj_kernel<<<dim3(256 / 128, 512 / 128), 256, 0, stream>>>(
        pred_in, WpredT, b_pred, predA, 256, 512, 640);

    // fused joint + output GEMM
    joint_kernel<<<dim3(65536 / 128, 1024 / 128), 256, 0, stream>>>(
        encA, predA, WoutT, b_out, out);
}